// Round 4
// baseline (1146.285 us; speedup 1.0000x reference)
//
#include <hip/hip_runtime.h>

#define S_LEN 3072
#define NHQ 16
#define NKVH 8
#define HDIM 256
#define WIN 2048
#define QKV_COLS 8192

typedef __bf16 bf16x8 __attribute__((ext_vector_type(8)));
typedef float f32x4 __attribute__((ext_vector_type(4)));

__device__ __forceinline__ unsigned short f2bf(float f) {
    union { float f; unsigned u; } v; v.f = f;
    unsigned r = v.u + 0x7FFFu + ((v.u >> 16) & 1u);
    return (unsigned short)(r >> 16);
}
__device__ __forceinline__ float bf2f(unsigned short u) {
    union { unsigned u; float f; } v; v.u = ((unsigned)u) << 16; return v.f;
}

typedef __attribute__((address_space(3))) void lds_void_t;
typedef const __attribute__((address_space(1))) void glb_void_t;
__device__ __forceinline__ void async16(const void* g, void* l) {
    __builtin_amdgcn_global_load_lds((glb_void_t*)g, (lds_void_t*)l, 16, 0, 0);
}

// ---------------- fp32 -> bf16 cast ----------------
__global__ __launch_bounds__(256) void cast_bf16_kernel(const float* __restrict__ src,
                                                        unsigned short* __restrict__ dst,
                                                        int n) {
    int i = (blockIdx.x * 256 + threadIdx.x) * 4;
    if (i >= n) return;
    float4 v = *(const float4*)(src + i);
    ushort4 o;
    o.x = f2bf(v.x); o.y = f2bf(v.y); o.z = f2bf(v.z); o.w = f2bf(v.w);
    *(ushort4*)(dst + i) = o;
}

// ---------------- bf16 GEMM: C[M,N] = A[M,K] @ B[N,K]^T ----------------
template <int OUT_BF16>
__global__ __launch_bounds__(256) void gemm_bt(const unsigned short* __restrict__ A,
                                               const unsigned short* __restrict__ B,
                                               void* __restrict__ Cv,
                                               int N, int K) {
    __shared__ __align__(16) unsigned short At[128 * 32];
    __shared__ __align__(16) unsigned short Bt[128 * 32];
    const int tid = threadIdx.x;
    const int wid = tid >> 6, lane = tid & 63;
    const int ln = lane & 15, quad = lane >> 4;
    const int bm = blockIdx.y, bn = blockIdx.x;
    const int wm = wid >> 1, wn = wid & 1;

    const f32x4 fzero = {0.f, 0.f, 0.f, 0.f};
    f32x4 acc[4][4];
#pragma unroll
    for (int i = 0; i < 4; i++) {
#pragma unroll
        for (int j = 0; j < 4; j++) acc[i][j] = fzero;
    }

    const unsigned short* gA = A + (size_t)(bm * 128 + wid * 32 + (lane >> 2)) * K + (lane & 3) * 8;
    const unsigned short* gB = B + (size_t)(bn * 128 + wid * 32 + (lane >> 2)) * K + (lane & 3) * 8;
    unsigned short* lA = At + wid * 32 * 32;
    unsigned short* lB = Bt + wid * 32 * 32;

    for (int k0 = 0; k0 < K; k0 += 32) {
        async16(gA + k0, lA);
        async16(gA + k0 + 16 * K, lA + 16 * 32);
        async16(gB + k0, lB);
        async16(gB + k0 + 16 * K, lB + 16 * 32);
        __syncthreads();

        bf16x8 af[4], bfr[4];
#pragma unroll
        for (int mt = 0; mt < 4; mt++)
            af[mt] = *(const bf16x8*)(At + (wm * 64 + mt * 16 + ln) * 32 + quad * 8);
#pragma unroll
        for (int nt = 0; nt < 4; nt++)
            bfr[nt] = *(const bf16x8*)(Bt + (wn * 64 + nt * 16 + ln) * 32 + quad * 8);
#pragma unroll
        for (int mt = 0; mt < 4; mt++) {
#pragma unroll
            for (int nt = 0; nt < 4; nt++)
                acc[mt][nt] = __builtin_amdgcn_mfma_f32_16x16x32_bf16(af[mt], bfr[nt], acc[mt][nt], 0, 0, 0);
        }
        __syncthreads();
    }

    const int row0 = bm * 128 + wm * 64 + quad * 4;
    const int col0 = bn * 128 + wn * 64 + ln;
    if (OUT_BF16) {
        unsigned short* C = (unsigned short*)Cv;
#pragma unroll
        for (int mt = 0; mt < 4; mt++) {
#pragma unroll
            for (int nt = 0; nt < 4; nt++) {
#pragma unroll
                for (int rr = 0; rr < 4; rr++)
                    C[(size_t)(row0 + mt * 16 + rr) * N + col0 + nt * 16] = f2bf(acc[mt][nt][rr]);
            }
        }
    } else {
        float* C = (float*)Cv;
#pragma unroll
        for (int mt = 0; mt < 4; mt++) {
#pragma unroll
            for (int nt = 0; nt < 4; nt++) {
#pragma unroll
                for (int rr = 0; rr < 4; rr++)
                    C[(size_t)(row0 + mt * 16 + rr) * N + col0 + nt * 16] = acc[mt][nt][rr];
            }
        }
    }
}

// ---------------- RoPE for Q (scaled) and K ----------------
__global__ __launch_bounds__(256) void rope_kernel(const unsigned short* __restrict__ qkv,
                                                   const float* __restrict__ freqs,
                                                   const int* __restrict__ kvidx,
                                                   unsigned short* __restrict__ Qb,
                                                   unsigned short* __restrict__ Kb) {
    int t = blockIdx.x * 256 + threadIdx.x;
    int d = t & 127;
    int t2 = t >> 7;
    int hh = t2 % 24;
    int pos = t2 / 24;
    if (pos >= S_LEN) return;
    float2 cs = *(const float2*)(freqs + ((size_t)pos * 128 + d) * 2);
    if (hh < NHQ) {
        const unsigned short* src = qkv + (size_t)pos * QKV_COLS + hh * HDIM + d;
        float x1 = bf2f(src[0]), x2 = bf2f(src[128]);
        float o1 = (x1 * cs.x - x2 * cs.y) * 0.0625f;
        float o2 = (x1 * cs.y + x2 * cs.x) * 0.0625f;
        unsigned short* dst = Qb + ((size_t)hh * S_LEN + pos) * HDIM + d;
        dst[0] = f2bf(o1);
        dst[128] = f2bf(o2);
    } else {
        int kvh = hh - NHQ;
        const unsigned short* src = qkv + (size_t)pos * QKV_COLS + NHQ * HDIM + kvh * HDIM + d;
        float x1 = bf2f(src[0]), x2 = bf2f(src[128]);
        float o1 = x1 * cs.x - x2 * cs.y;
        float o2 = x1 * cs.y + x2 * cs.x;
        int wpos = kvidx[pos];
        unsigned short* dst = Kb + ((size_t)kvh * S_LEN + wpos) * HDIM + d;
        dst[0] = f2bf(o1);
        dst[128] = f2bf(o2);
    }
}

// ---------------- V transpose ----------------
__global__ __launch_bounds__(256) void vtrans_kernel(const unsigned short* __restrict__ qkv,
                                                     const int* __restrict__ kvidx,
                                                     unsigned short* __restrict__ Vbt) {
    __shared__ unsigned short T[64][72];
    int pos0 = blockIdx.x * 64;
    int c0 = blockIdx.y * 64;
    int a = threadIdx.x >> 6;
    int b = threadIdx.x & 63;
#pragma unroll
    for (int r = 0; r < 16; r++) {
        int pl = r * 4 + a;
        T[pl][b] = qkv[(size_t)(pos0 + pl) * QKV_COLS + 6144 + c0 + b];
    }
    __syncthreads();
    int wpos = kvidx[pos0 + b];
#pragma unroll
    for (int r = 0; r < 16; r++) {
        int cl = r * 4 + a;
        Vbt[(size_t)(c0 + cl) * S_LEN + wpos] = T[b][cl];
    }
}

// ---------------- flash attention v4: barrier-free, direct global fragments --------
// Waves fully independent: each wave owns 32 q-rows x one key-chunk (<=16 tiles
// of 32 keys). K and V^T fragments are coalesced 16B global loads (L2-resident:
// K+V = 25MB < 32MB L2) -> no LDS staging, no __syncthreads. Only LDS use is
// the per-wave P C-layout -> A-layout round trip. Fixed-max softmax (softcap
// bounds scores) => partials combine by addition (atomicAdd for nc>1).
__global__ __launch_bounds__(256, 2) void attn_kernel(const unsigned short* __restrict__ Qb,
                                                      const unsigned short* __restrict__ Kb,
                                                      const unsigned short* __restrict__ Vbt,
                                                      float* __restrict__ Acc,
                                                      float* __restrict__ Ps,
                                                      unsigned short* __restrict__ attn_out) {
    __shared__ __align__(16) unsigned short Pl[4][2][16][40];

    const int tid = threadIdx.x;
    const int wid = tid >> 6, lane = tid & 63;
    const int ln = lane & 15, quad = lane >> 4;

    // decode wave job (reversed: long chunks dispatch first)
    const int w = 5119 - (blockIdx.x * 4 + wid);
    const int h = w / 320;
    const int rem = w % 320;
    int qt, sub, nc;
    if (rem < 16)       { qt = rem; sub = 0; nc = 1; }
    else if (rem < 48)  { int e = rem - 16;  qt = 16 + (e >> 1); sub = e & 1; nc = 2; }
    else if (rem < 96)  { int e = rem - 48;  qt = 32 + e / 3;    sub = e % 3; nc = 3; }
    else if (rem < 160) { int e = rem - 96;  qt = 48 + (e >> 2); sub = e & 3; nc = 4; }
    else                { int e = rem - 160; qt = 64 + e / 5;    sub = e % 5; nc = 5; }

    const int kv = h >> 1;
    const int imin = qt * 32;
    const int imax = imin + 31;

    const int t_lo = (qt > 64) ? (qt - 64) : 0;
    const int tn = qt - t_lo + 1;
    const int ts = t_lo + (tn * sub) / nc;
    const int te = t_lo + (tn * (sub + 1)) / nc;

    // Q fragments for two 16-row m-tiles (A layout: m=ln, k=quad*8+j)
    bf16x8 qf0[8], qf1[8];
    {
        const unsigned short* q0p = Qb + ((size_t)h * S_LEN + imin + ln) * HDIM + quad * 8;
#pragma unroll
        for (int k0 = 0; k0 < 8; k0++) qf0[k0] = *(const bf16x8*)(q0p + k0 * 32);
        const unsigned short* q1p = q0p + 16 * HDIM;
#pragma unroll
        for (int k0 = 0; k0 < 8; k0++) qf1[k0] = *(const bf16x8*)(q1p + k0 * 32);
    }

    const f32x4 fzero = {0.f, 0.f, 0.f, 0.f};
    f32x4 acc0[16], acc1[16];
#pragma unroll
    for (int t = 0; t < 16; t++) { acc0[t] = fzero; acc1[t] = fzero; }
    float ps0[4] = {0.f, 0.f, 0.f, 0.f};
    float ps1[4] = {0.f, 0.f, 0.f, 0.f};

    const unsigned short* kbase = Kb + ((size_t)kv * S_LEN + ln) * HDIM + quad * 8;
    const unsigned short* vbase = Vbt + ((size_t)kv * HDIM + ln) * S_LEN + quad * 8;

    for (int tt = ts; tt < te; tt++) {
        const int p0 = tt * 32;

        // S = Q K^T : 2 m-tiles x 2 col-tiles (keys p0+c*16+ln)
        f32x4 s00 = fzero, s10 = fzero, s01 = fzero, s11 = fzero;
        {
            const unsigned short* kp = kbase + (size_t)p0 * HDIM;
#pragma unroll
            for (int k0 = 0; k0 < 8; k0++) {
                bf16x8 kf = *(const bf16x8*)(kp + k0 * 32);
                s00 = __builtin_amdgcn_mfma_f32_16x16x32_bf16(qf0[k0], kf, s00, 0, 0, 0);
                s10 = __builtin_amdgcn_mfma_f32_16x16x32_bf16(qf1[k0], kf, s10, 0, 0, 0);
            }
            const unsigned short* kp1 = kp + 16 * HDIM;
#pragma unroll
            for (int k0 = 0; k0 < 8; k0++) {
                bf16x8 kf = *(const bf16x8*)(kp1 + k0 * 32);
                s01 = __builtin_amdgcn_mfma_f32_16x16x32_bf16(qf0[k0], kf, s01, 0, 0, 0);
                s11 = __builtin_amdgcn_mfma_f32_16x16x32_bf16(qf1[k0], kf, s11, 0, 0, 0);
            }
        }

        const bool full = (p0 + 31 <= imin) && (p0 >= imax - WIN + 1);
#pragma unroll
        for (int m = 0; m < 2; m++) {
            f32x4 sa = m ? s10 : s00;
            f32x4 sb = m ? s11 : s01;
            float* ps = m ? ps1 : ps0;
#pragma unroll
            for (int r = 0; r < 4; r++) {
                // p = exp(50*tanh(s/50)) via z=e^{2s/50}: tanh = 1 - 2/(z+1)
                float z0 = __expf(sa[r] * 0.04f);
                float z1 = __expf(sb[r] * 0.04f);
                float t0 = fmaf(-100.f, __builtin_amdgcn_rcpf(z0 + 1.f), 50.f);
                float t1 = fmaf(-100.f, __builtin_amdgcn_rcpf(z1 + 1.f), 50.f);
                float p0v = __expf(t0);
                float p1v = __expf(t1);
                if (!full) {
                    const int i = imin + m * 16 + quad * 4 + r;
                    int j0 = p0 + ln, j1 = p0 + 16 + ln;
                    p0v = ((j0 <= i) && (j0 + WIN > i)) ? p0v : 0.f;
                    p1v = ((j1 <= i) && (j1 + WIN > i)) ? p1v : 0.f;
                }
                ps[r] += p0v + p1v;
                Pl[wid][m][quad * 4 + r][ln] = f2bf(p0v);
                Pl[wid][m][quad * 4 + r][16 + ln] = f2bf(p1v);
            }
        }
        // P in A-layout (same-wave LDS round trip; lgkmcnt ordering)
        bf16x8 pa0 = *(const bf16x8*)(&Pl[wid][0][ln][quad * 8]);
        bf16x8 pa1 = *(const bf16x8*)(&Pl[wid][1][ln][quad * 8]);
        const unsigned short* vp = vbase + p0;
#pragma unroll
        for (int t = 0; t < 16; t++) {
            bf16x8 vb = *(const bf16x8*)(vp + (size_t)t * 16 * S_LEN);
            acc0[t] = __builtin_amdgcn_mfma_f32_16x16x32_bf16(pa0, vb, acc0[t], 0, 0, 0);
            acc1[t] = __builtin_amdgcn_mfma_f32_16x16x32_bf16(pa1, vb, acc1[t], 0, 0, 0);
        }
    }

    // reduce ps across the 16 lanes of each quad-row group
    float psr0[4], psr1[4];
#pragma unroll
    for (int r = 0; r < 4; r++) {
        float a = ps0[r], b = ps1[r];
#pragma unroll
        for (int o = 1; o <= 8; o <<= 1) { a += __shfl_xor(a, o); b += __shfl_xor(b, o); }
        psr0[r] = a; psr1[r] = b;
    }

    if (nc == 1) {
#pragma unroll
        for (int t = 0; t < 16; t++) {
#pragma unroll
            for (int r = 0; r < 4; r++) {
                int i0 = imin + quad * 4 + r;
                attn_out[(size_t)i0 * 4096 + h * HDIM + t * 16 + ln] =
                    f2bf(acc0[t][r] * __builtin_amdgcn_rcpf(psr0[r]));
                attn_out[(size_t)(i0 + 16) * 4096 + h * HDIM + t * 16 + ln] =
                    f2bf(acc1[t][r] * __builtin_amdgcn_rcpf(psr1[r]));
            }
        }
    } else {
        if (ln == 0) {
#pragma unroll
            for (int r = 0; r < 4; r++) {
                atomicAdd(&Ps[h * S_LEN + imin + quad * 4 + r], psr0[r]);
                atomicAdd(&Ps[h * S_LEN + imin + 16 + quad * 4 + r], psr1[r]);
            }
        }
#pragma unroll
        for (int t = 0; t < 16; t++) {
#pragma unroll
            for (int r = 0; r < 4; r++) {
                int i0 = imin + quad * 4 + r;
                atomicAdd(&Acc[((size_t)h * S_LEN + i0) * HDIM + t * 16 + ln], acc0[t][r]);
                atomicAdd(&Acc[((size_t)h * S_LEN + i0 + 16) * HDIM + t * 16 + ln], acc1[t][r]);
            }
        }
    }
}

// ---------------- normalize chunked rows (pos >= 512) ----------------
__global__ __launch_bounds__(256) void norm_kernel(const float* __restrict__ Acc,
                                                   const float* __restrict__ Ps,
                                                   unsigned short* __restrict__ attn_out) {
    int row = blockIdx.x * 4 + (threadIdx.x >> 6);   // over 16*2560 rows
    int lane = threadIdx.x & 63;
    int h = row / 2560;
    int pos = 512 + (row % 2560);
    float4 a = *(const float4*)(Acc + ((size_t)h * S_LEN + pos) * HDIM + lane * 4);
    float inv = __builtin_amdgcn_rcpf(Ps[h * S_LEN + pos]);
    ushort4 o;
    o.x = f2bf(a.x * inv); o.y = f2bf(a.y * inv);
    o.z = f2bf(a.z * inv); o.w = f2bf(a.w * inv);
    *(ushort4*)(attn_out + (size_t)pos * 4096 + h * HDIM + lane * 4) = o;
}

// ---------------- launch ----------------
extern "C" void kernel_launch(void* const* d_in, const int* in_sizes, int n_in,
                              void* d_out, int out_size, void* d_ws, size_t ws_size,
                              hipStream_t stream) {
    (void)in_sizes; (void)n_in; (void)out_size; (void)ws_size;
    const float* hidden = (const float*)d_in[0];
    const float* freqs  = (const float*)d_in[1];
    const int* kvidx    = (const int*)d_in[2];
    const float* qkv_w  = (const float*)d_in[6];
    const float* o_w    = (const float*)d_in[7];
    float* out = (float*)d_out;

    char* ws = (char*)d_ws;
    unsigned short* hs_bf   = (unsigned short*)(ws);                 // Ps reuses after gemm1
    unsigned short* w1_bf   = (unsigned short*)(ws + 22020096);
    unsigned short* w2_bf   = (unsigned short*)(ws + 80740352);
    unsigned short* qkv_bf  = (unsigned short*)(ws + 110100480);     // Acc reuses after rope/vtrans
    unsigned short* Qb      = (unsigned short*)(ws + 160432128);
    unsigned short* Kb      = (unsigned short*)(ws + 185597952);
    unsigned short* Vbt     = (unsigned short*)(ws + 198180864);
    unsigned short* attn_bf = (unsigned short*)(ws + 210763776);

    float* Acc = (float*)(ws + 110100480);   // 16*3072*256*4 = 50,331,648 B exactly
    float* Ps  = (float*)(ws);               // 16*3072*4 = 196,608 B

    cast_bf16_kernel<<<10752, 256, 0, stream>>>(hidden, hs_bf, 11010048);
    cast_bf16_kernel<<<28672, 256, 0, stream>>>(qkv_w, w1_bf, 29360128);
    cast_bf16_kernel<<<14336, 256, 0, stream>>>(o_w, w2_bf, 14680064);

    gemm_bt<1><<<dim3(64, 24), 256, 0, stream>>>(hs_bf, w1_bf, (void*)qkv_bf, 8192, 3584);

    rope_kernel<<<36864, 256, 0, stream>>>(qkv_bf, freqs, kvidx, Qb, Kb);
    vtrans_kernel<<<dim3(48, 32), 256, 0, stream>>>(qkv_bf, kvidx, Vbt);

    hipMemsetAsync(Acc, 0, (size_t)16 * 3072 * 256 * 4, stream);
    hipMemsetAsync(Ps, 0, (size_t)16 * 3072 * 4, stream);

    attn_kernel<<<1280, 256, 0, stream>>>(Qb, Kb, Vbt, Acc, Ps, attn_bf);
    norm_kernel<<<10240, 256, 0, stream>>>(Acc, Ps, attn_bf);

    gemm_bt<0><<<dim3(28, 24), 256, 0, stream>>>(attn_bf, w2_bf, (void*)out, 3584, 4096);
}